// Round 13
// baseline (457.754 us; speedup 1.0000x reference)
//
#include <hip/hip_runtime.h>
#include <math.h>

#define KNN 16
#define G 32
#define G3 32768
#define MRING 31
#define FLTMAX 3.402823466e+38f

typedef __attribute__((ext_vector_type(8))) short short8x;   // 8 x bf16 frag
typedef __attribute__((ext_vector_type(4))) float f32x4;     // MFMA accum

// ---------- bf16 helpers (RNE) ----------
__device__ __forceinline__ unsigned short bf16rn(float x) {
  unsigned u = __float_as_uint(x);
  unsigned r = (u + 0x7FFFu + ((u >> 16) & 1u)) >> 16;
  return (unsigned short)r;
}
__device__ __forceinline__ float bf16tof(unsigned short h) {
  return __uint_as_float(((unsigned)h) << 16);
}

// ---------- order-preserving float<->uint keys ----------
__device__ __forceinline__ unsigned fkey(float f) {
  unsigned u = __float_as_uint(f);
  return (u & 0x80000000u) ? ~u : (u | 0x80000000u);
}
__device__ __forceinline__ float funkey(unsigned u) {
  unsigned b = (u & 0x80000000u) ? (u & 0x7FFFFFFFu) : ~u;
  return __uint_as_float(b);
}

__device__ __forceinline__ void cell_of(float x, float y, float z, const float* P,
                                        int& cx, int& cy, int& cz) {
  cx = min(G - 1, max(0, (int)((x - P[0]) * P[3])));
  cy = min(G - 1, max(0, (int)((y - P[1]) * P[4])));
  cz = min(G - 1, max(0, (int)((z - P[2]) * P[5])));
}

// ---------- stage 1: zero grids + pack centers (init merged) ----------
// sq EXACTLY as R1..R12 (absmax-stable): (x*x + y*y) + z*z, contract off.
__global__ void prep_kernel(const float* __restrict__ centers,
                            float4* __restrict__ cpack, int* __restrict__ deg,
                            int* __restrict__ counts, int* __restrict__ cursor,
                            int n) {
  #pragma clang fp contract(off)
  int t = blockIdx.x * blockDim.x + threadIdx.x;
  if (t < G3) counts[t] = 0;
  else cursor[t - G3] = 0;
  if (t < n) {
    float x = centers[3 * t], y = centers[3 * t + 1], z = centers[3 * t + 2];
    float sq = (x * x + y * y) + z * z;
    cpack[t] = make_float4(x, y, z, sq);
    deg[t] = 0;
  }
}

// ---------- stage 2: bbox reduction + grid params, one block -------------
__global__ __launch_bounds__(1024) void params_kernel(const float4* __restrict__ cpack,
                                                      float* __restrict__ P, int n) {
  __shared__ float sminb[16][3], smaxb[16][3];
  int tid = threadIdx.x;
  float mnx = FLTMAX, mny = FLTMAX, mnz = FLTMAX;
  float mxx = -FLTMAX, mxy = -FLTMAX, mxz = -FLTMAX;
  for (int i = tid; i < n; i += 1024) {
    float4 c = cpack[i];
    mnx = fminf(mnx, c.x); mny = fminf(mny, c.y); mnz = fminf(mnz, c.z);
    mxx = fmaxf(mxx, c.x); mxy = fmaxf(mxy, c.y); mxz = fmaxf(mxz, c.z);
  }
  #pragma unroll
  for (int off = 1; off < 64; off <<= 1) {
    mnx = fminf(mnx, __shfl_xor(mnx, off));
    mny = fminf(mny, __shfl_xor(mny, off));
    mnz = fminf(mnz, __shfl_xor(mnz, off));
    mxx = fmaxf(mxx, __shfl_xor(mxx, off));
    mxy = fmaxf(mxy, __shfl_xor(mxy, off));
    mxz = fmaxf(mxz, __shfl_xor(mxz, off));
  }
  if ((tid & 63) == 0) {
    int w = tid >> 6;
    sminb[w][0] = mnx; sminb[w][1] = mny; sminb[w][2] = mnz;
    smaxb[w][0] = mxx; smaxb[w][1] = mxy; smaxb[w][2] = mxz;
  }
  __syncthreads();
  if (tid == 0) {
    float xmin = sminb[0][0], ymin = sminb[0][1], zmin = sminb[0][2];
    float xmax = smaxb[0][0], ymax = smaxb[0][1], zmax = smaxb[0][2];
    for (int w = 1; w < 16; ++w) {
      xmin = fminf(xmin, sminb[w][0]); ymin = fminf(ymin, sminb[w][1]);
      zmin = fminf(zmin, sminb[w][2]);
      xmax = fmaxf(xmax, smaxb[w][0]); ymax = fmaxf(ymax, smaxb[w][1]);
      zmax = fmaxf(zmax, smaxb[w][2]);
    }
    float ex = fmaxf(xmax - xmin, 1e-9f);
    float ey = fmaxf(ymax - ymin, 1e-9f);
    float ez = fmaxf(zmax - zmin, 1e-9f);
    P[0] = xmin; P[1] = ymin; P[2] = zmin;
    P[3] = (float)G / ex; P[4] = (float)G / ey; P[5] = (float)G / ez;
    P[6] = ex / (float)G; P[7] = ey / (float)G; P[8] = ez / (float)G;
    P[9] = fminf(P[6], fminf(P[7], P[8]));
  }
}

// ---------- stage 3 ----------
__global__ void count_kernel(const float4* __restrict__ cpack, const float* __restrict__ P,
                             int* __restrict__ counts, int n) {
  int i = blockIdx.x * blockDim.x + threadIdx.x;
  if (i >= n) return;
  float4 c = cpack[i];
  int cx, cy, cz; cell_of(c.x, c.y, c.z, P, cx, cy, cz);
  atomicAdd(&counts[(cz * G + cy) * G + cx], 1);
}

// ---------- stage 4: scan + fused (start,count) ----------
__global__ __launch_bounds__(1024) void scan_kernel(const int* __restrict__ counts,
                                                    int* __restrict__ starts,
                                                    int2* __restrict__ cellinfo) {
  __shared__ int sh[1024];
  int t = threadIdx.x;
  int base = t * 32;
  int loc[32];
  int cnts[32];
  int s = 0;
  #pragma unroll
  for (int u = 0; u < 32; ++u) {
    cnts[u] = counts[base + u];
    loc[u] = s; s += cnts[u];
  }
  sh[t] = s;
  __syncthreads();
  for (int off = 1; off < 1024; off <<= 1) {
    int v = (t >= off) ? sh[t - off] : 0;
    __syncthreads();
    sh[t] += v;
    __syncthreads();
  }
  int pre = (t == 0) ? 0 : sh[t - 1];
  #pragma unroll
  for (int u = 0; u < 32; ++u) {
    int st = pre + loc[u];
    starts[base + u] = st;
    cellinfo[base + u] = make_int2(st, cnts[u]);
  }
}

// ---------- stage 5: scatter + inverse permutation ----------
__global__ void scatter_kernel(const float4* __restrict__ cpack, const float* __restrict__ P,
                               const int* __restrict__ starts, int* __restrict__ cursor,
                               int* __restrict__ sid, int* __restrict__ inv,
                               float4* __restrict__ spack, int n) {
  int i = blockIdx.x * blockDim.x + threadIdx.x;
  if (i >= n) return;
  float4 c = cpack[i];
  int cx, cy, cz; cell_of(c.x, c.y, c.z, P, cx, cy, cz);
  int cell = (cz * G + cy) * G + cx;
  int slot = starts[cell] + atomicAdd(&cursor[cell], 1);
  sid[slot] = i;
  inv[i] = slot;
  spack[slot] = c;
}

// ---------- stage 6: expanding-ring exact kNN (R12 verbatim) ----------
__global__ __launch_bounds__(64) void query_kernel(
    const float4* __restrict__ spack, const int* __restrict__ sid,
    const int* __restrict__ inv, const int2* __restrict__ cellinfo,
    const float* __restrict__ P, int* __restrict__ knn_idx,
    int* __restrict__ deg, int n) {
  #pragma clang fp contract(off)
  __shared__ unsigned long long lsk[KNN][64];  // 8192 B
  const int lane = threadIdx.x;
  const int g = blockIdx.x;
  if (g >= n) return;
  const float4 q = spack[g];
  const float xmin = P[0], ymin = P[1], zmin = P[2];
  const float wx = P[6], wy = P[7], wz = P[8], wmin = P[9];
  int cx, cy, cz; cell_of(q.x, q.y, q.z, P, cx, cy, cz);

  int cnt = 0;
  unsigned long long wkey = 0; int wslot = 0;
  unsigned long long minkey = ~0ull; int minslot = 0;

  for (int m = 1; m <= MRING; ++m) {
    if (m >= 2) {
      float b = (float)(m - 1) * wmin;
      float b2 = b * b * 0.999f;
      unsigned long long tk = ((unsigned long long)fkey(b2)) << 32;
      int c = 0;
      for (int t = 0; t < cnt; ++t) c += (lsk[t][lane] < tk) ? 1 : 0;
      #pragma unroll
      for (int off = 1; off < 64; off <<= 1) c += __shfl_xor(c, off);
      if (c >= KNN) break;
    }
    float lw = (cnt == KNN) ? funkey((unsigned)(wkey >> 32)) : FLTMAX;
    #pragma unroll
    for (int off = 1; off < 64; off <<= 1) lw = fminf(lw, __shfl_xor(lw, off));
    const bool do_prune = (lw < FLTMAX);  // wave-uniform

    const int ncells = (m == 1) ? 27 : (24 * m * m + 2);
    for (int cb = 0; cb < ncells; cb += 64) {
      int f = cb + lane;
      int ccnt = 0, cs0 = 0;
      if (f < ncells) {
        int dx, dy, dz;
        if (m == 1) {
          dz = f / 9 - 1; int rem = f % 9; dy = rem / 3 - 1; dx = rem % 3 - 1;
        } else {
          int side = 2 * m + 1;
          int S1 = side * side;
          if (f < 2 * S1) {
            dz = (f < S1) ? -m : m;
            int i2 = (f < S1) ? f : f - S1;
            dy = i2 / side - m; dx = i2 % side - m;
          } else {
            int r = f - 2 * S1;
            int layer = r / (8 * m);
            int t2 = r - layer * 8 * m;
            dz = layer - (m - 1);
            if (t2 < side) { dy = -m; dx = t2 - m; }
            else if (t2 < 2 * side) { dy = m; dx = (t2 - side) - m; }
            else { int u = t2 - 2 * side; dx = (u & 1) ? m : -m; dy = (u >> 1) - (m - 1); }
          }
        }
        int x = cx + dx, y = cy + dy, z = cz + dz;
        if (x >= 0 && x < G && y >= 0 && y < G && z >= 0 && z < G) {
          int cell = (z * G + y) * G + x;
          int2 ci = cellinfo[cell];
          if (ci.y > 0) {
            bool pass = true;
            if (do_prune) {
              float lox = xmin + (float)x * wx;
              float loy = ymin + (float)y * wy;
              float loz = zmin + (float)z * wz;
              float ddx = fmaxf(fmaxf(lox - q.x, q.x - (lox + wx)), 0.f);
              float ddy = fmaxf(fmaxf(loy - q.y, q.y - (loy + wy)), 0.f);
              float ddz = fmaxf(fmaxf(loz - q.z, q.z - (loz + wz)), 0.f);
              float cd2 = ddx * ddx + ddy * ddy + ddz * ddz;
              pass = !(cd2 * 0.999f > lw);
            }
            if (pass) { ccnt = ci.y; cs0 = ci.x; }
          }
        }
      }
      int inc = ccnt;
      #pragma unroll
      for (int off = 1; off < 64; off <<= 1) {
        int t = __shfl_up(inc, off);
        if (lane >= off) inc += t;
      }
      int total = __shfl(inc, 63);
      if (total == 0) continue;
      unsigned seg = ((unsigned)(inc - ccnt) << 16) | (unsigned)cs0;
      const int tmax = total - 1;

      int fc = lane;
      int fcc = min(fc, tmax);
      int lo = 0;
      #pragma unroll
      for (int s = 32; s >= 1; s >>= 1) {
        int cand = lo + s;
        unsigned o = __shfl(seg, cand & 63);
        if (cand < 64 && (int)(o >> 16) <= fcc) lo = cand;
      }
      unsigned o2 = __shfl(seg, lo);
      int src = (int)(o2 & 0xFFFFu) + (fcc - (int)(o2 >> 16));
      float4 c4 = spack[src];
      int j = sid[src];
      const int nloop = (total + 63) >> 6;
      for (int it = 0; it < nloop; ++it) {
        int fn = fc + 64;
        int fnc = min(fn, tmax);
        int lo2 = 0;
        #pragma unroll
        for (int s = 32; s >= 1; s >>= 1) {
          int cand = lo2 + s;
          unsigned o = __shfl(seg, cand & 63);
          if (cand < 64 && (int)(o >> 16) <= fnc) lo2 = cand;
        }
        unsigned o3 = __shfl(seg, lo2);
        int srcn = (int)(o3 & 0xFFFFu) + (fnc - (int)(o3 >> 16));
        float4 c4n = spack[srcn];
        int jn = sid[srcn];
        if (fc < total) {
          float dot = fmaf(q.z, c4.z, fmaf(q.y, c4.y, q.x * c4.x));
          float d2 = (q.w + c4.w) - 2.0f * dot;
          unsigned long long key =
              (((unsigned long long)fkey(d2)) << 32) | (unsigned)j;
          if (cnt < KNN) {
            lsk[cnt][lane] = key;
            if (key < minkey) { minkey = key; minslot = cnt; }
            ++cnt;
            if (cnt == KNN) {
              wkey = 0; wslot = 0;
              #pragma unroll
              for (int u = 0; u < KNN; ++u) {
                unsigned long long k2 = lsk[u][lane];
                if (k2 > wkey) { wkey = k2; wslot = u; }
              }
            }
          } else if (key < wkey) {
            lsk[wslot][lane] = key;
            if (key < minkey) { minkey = key; minslot = wslot; }
            wkey = 0;
            #pragma unroll
            for (int u = 0; u < KNN; ++u) {
              unsigned long long k2 = lsk[u][lane];
              if (k2 > wkey) { wkey = k2; wslot = u; }
            }
          }
        }
        fc = fn; c4 = c4n; j = jn;
      }
    }
  }

  unsigned long long mykey = 0;
  for (int t = 0; t < KNN; ++t) {
    unsigned long long k = minkey; int src = lane;
    #pragma unroll
    for (int off = 1; off < 64; off <<= 1) {
      unsigned long long ok = __shfl_xor(k, off);
      int os = __shfl_xor(src, off);
      if (ok < k) { k = ok; src = os; }
    }
    if (lane == t) mykey = k;
    if (lane == src) {
      lsk[minslot][lane] = ~0ull;
      minkey = ~0ull; minslot = 0;
      for (int u = 0; u < cnt; ++u) {
        unsigned long long kk = lsk[u][lane];
        if (kk < minkey) { minkey = kk; minslot = u; }
      }
    }
  }
  if (lane < KNN) {
    int j = (int)(unsigned)(mykey & 0xFFFFFFFFull);
    int js = inv[j];
    knn_idx[g * KNN + lane] = js;
    atomicAdd(&deg[js], 1);
  }
}

__global__ void norm_kernel(const int* __restrict__ deg, float* __restrict__ srcn, int n) {
  int i = blockIdx.x * blockDim.x + threadIdx.x;
  if (i < n) {
    float d = (float)max(deg[i], 1);
    srcn[i] = 1.0f / sqrtf(d);
  }
}

// ---------- W split: fp32 W[K][256] -> frag-octet-blocked bf16 hi/lo ------
__global__ void split_w_kernel(const float* __restrict__ W,
                               unsigned short* __restrict__ wbh,
                               unsigned short* __restrict__ wbl, int K) {
  int t = blockIdx.x * blockDim.x + threadIdx.x;
  int noct = (K >> 5) * 1024;
  if (t >= noct) return;
  int kblk = t >> 10;
  int g = (t >> 6) & 15;
  int l = t & 63;
  int n = ((g >> 2) << 6) + ((g & 3) << 4) + (l & 15);
  int kbase = (kblk << 5) + ((l >> 4) << 3);
  #pragma unroll
  for (int j = 0; j < 8; ++j) {
    float w = W[(kbase + j) * 256 + n];
    unsigned short hi = bf16rn(w);
    wbh[t * 8 + j] = hi;
    wbl[t * 8 + j] = bf16rn(w - bf16tof(hi));
  }
}

// XCD-locality swizzle (grid must be multiple of 8).
__device__ __forceinline__ int xcd_swizzle(int b, int grid8) {
  int nch = grid8 >> 3;
  return (b & 7) * nch + (b >> 3);
}

// ---------- FUSED agg + split-bf16 MFMA GEMM (+ optional fused final) -----
// Phase 1: block aggregates ITS OWN 32 rows (bit-identical arithmetic to the
// old agg_kernel: rank-order fmaf chain, 0.25 scale, bf16 hi/lo split) into
// padded LDS. Phase 2: K-loop with A frags from LDS (2-way banks, free) and
// B octets loaded straight from blocked global W (no cross-wave sharing ->
// LDS staging removed; no __syncthreads in the K-loop).
template <int Kd>
__global__ __launch_bounds__(256) void agg_gemm(
    const float* __restrict__ h, const int* __restrict__ rmap,
    const float* __restrict__ srcn, const int* __restrict__ idx,
    const unsigned short* __restrict__ wbh, const unsigned short* __restrict__ wbl,
    const float* __restrict__ bias, float* __restrict__ C, int M,
    const float* __restrict__ Wf, const float* __restrict__ bfp,
    const int* __restrict__ sid, float* __restrict__ outp) {
  constexpr int S = Kd + 8;  // u16 stride pad: 17/33 dword-groups -> 2-way banks
  __shared__ unsigned short af_h[32][S];
  __shared__ unsigned short af_l[32][S];
  __shared__ float fred[32][4];
  const int tid = threadIdx.x;
  const int lane = tid & 63;
  const int w = tid >> 6;
  const int eb = xcd_swizzle(blockIdx.x, gridDim.x);
  const int mt0 = eb * 32;
  if (mt0 >= M) return;

  // ----- phase 1: aggregate rows mt0..mt0+31 into LDS (bf16 hi/lo) -----
  for (int r = w; r < 32; r += 4) {
    int i = mt0 + r;
    if (i < M) {
      if constexpr (Kd == 256) {
        float4 acc = make_float4(0.f, 0.f, 0.f, 0.f);
        #pragma unroll
        for (int k = 0; k < KNN; ++k) {
          int s = idx[i * KNN + k];
          float sn = srcn[s];
          int row = rmap ? rmap[s] : s;
          float4 hv = ((const float4*)(h + (size_t)row * Kd))[lane];
          acc.x = fmaf(sn, hv.x, acc.x);
          acc.y = fmaf(sn, hv.y, acc.y);
          acc.z = fmaf(sn, hv.z, acc.z);
          acc.w = fmaf(sn, hv.w, acc.w);
        }
        acc.x *= 0.25f; acc.y *= 0.25f; acc.z *= 0.25f; acc.w *= 0.25f;
        ushort4 hh, ll;
        hh.x = bf16rn(acc.x); ll.x = bf16rn(acc.x - bf16tof(hh.x));
        hh.y = bf16rn(acc.y); ll.y = bf16rn(acc.y - bf16tof(hh.y));
        hh.z = bf16rn(acc.z); ll.z = bf16rn(acc.z - bf16tof(hh.z));
        hh.w = bf16rn(acc.w); ll.w = bf16rn(acc.w - bf16tof(hh.w));
        *(ushort4*)&af_h[r][lane * 4] = hh;
        *(ushort4*)&af_l[r][lane * 4] = ll;
      } else {
        float2 acc = make_float2(0.f, 0.f);
        #pragma unroll
        for (int k = 0; k < KNN; ++k) {
          int s = idx[i * KNN + k];
          float sn = srcn[s];
          int row = rmap ? rmap[s] : s;
          float2 hv = ((const float2*)(h + (size_t)row * Kd))[lane];
          acc.x = fmaf(sn, hv.x, acc.x);
          acc.y = fmaf(sn, hv.y, acc.y);
        }
        acc.x *= 0.25f; acc.y *= 0.25f;
        ushort2 hh, ll;
        hh.x = bf16rn(acc.x); ll.x = bf16rn(acc.x - bf16tof(hh.x));
        hh.y = bf16rn(acc.y); ll.y = bf16rn(acc.y - bf16tof(hh.y));
        *(ushort2*)&af_h[r][lane * 2] = hh;
        *(ushort2*)&af_l[r][lane * 2] = ll;
      }
    } else {
      // zero pad rows beyond M
      if constexpr (Kd == 256) {
        ushort4 z = {0, 0, 0, 0};
        *(ushort4*)&af_h[r][lane * 4] = z;
        *(ushort4*)&af_l[r][lane * 4] = z;
      } else {
        ushort2 z = {0, 0};
        *(ushort2*)&af_h[r][lane * 2] = z;
        *(ushort2*)&af_l[r][lane * 2] = z;
      }
    }
  }
  __syncthreads();

  // ----- phase 2: MFMA K-loop, A from LDS, B direct from global -----
  f32x4 acc[2][4];
  #pragma unroll
  for (int ms = 0; ms < 2; ++ms)
    #pragma unroll
    for (int ns = 0; ns < 4; ++ns) acc[ms][ns] = (f32x4){0.f, 0.f, 0.f, 0.f};

  const int r0 = lane & 15;          // A row within sub-tile
  const int koct = lane >> 4;        // k-octet 0..3
  const int nkb = Kd >> 5;
  for (int kit = 0; kit < nkb; ++kit) {
    const int kk = (kit << 5) + (koct << 3);
    short8x a_h0 = *(const short8x*)&af_h[r0][kk];
    short8x a_l0 = *(const short8x*)&af_l[r0][kk];
    short8x a_h1 = *(const short8x*)&af_h[16 + r0][kk];
    short8x a_l1 = *(const short8x*)&af_l[16 + r0][kk];
    short8x bh[4], bl[4];
    #pragma unroll
    for (int ns = 0; ns < 4; ++ns) {
      size_t boff = (((size_t)kit * 16 + (w * 4 + ns)) * 64 + lane) * 8;
      bh[ns] = *(const short8x*)(wbh + boff);
      bl[ns] = *(const short8x*)(wbl + boff);
    }
    #pragma unroll
    for (int ns = 0; ns < 4; ++ns) {
      acc[0][ns] = __builtin_amdgcn_mfma_f32_16x16x32_bf16(a_h0, bh[ns], acc[0][ns], 0, 0, 0);
      acc[0][ns] = __builtin_amdgcn_mfma_f32_16x16x32_bf16(a_h0, bl[ns], acc[0][ns], 0, 0, 0);
      acc[0][ns] = __builtin_amdgcn_mfma_f32_16x16x32_bf16(a_l0, bh[ns], acc[0][ns], 0, 0, 0);
      acc[1][ns] = __builtin_amdgcn_mfma_f32_16x16x32_bf16(a_h1, bh[ns], acc[1][ns], 0, 0, 0);
      acc[1][ns] = __builtin_amdgcn_mfma_f32_16x16x32_bf16(a_h1, bl[ns], acc[1][ns], 0, 0, 0);
      acc[1][ns] = __builtin_amdgcn_mfma_f32_16x16x32_bf16(a_l1, bh[ns], acc[1][ns], 0, 0, 0);
    }
  }

  const int col = lane & 15;
  const int rq = lane >> 4;
  if (Wf) {
    // fused final: logits = relu(C) @ Wf + bf, sigmoid, scatter to out
    float pr[2][4];
    #pragma unroll
    for (int ms = 0; ms < 2; ++ms)
      #pragma unroll
      for (int r = 0; r < 4; ++r) pr[ms][r] = 0.f;
    #pragma unroll
    for (int ns = 0; ns < 4; ++ns) {
      int nn = (w << 6) + (ns << 4) + col;
      float bi = bias[nn];
      float wv = Wf[nn];
      #pragma unroll
      for (int ms = 0; ms < 2; ++ms)
        #pragma unroll
        for (int r = 0; r < 4; ++r)
          pr[ms][r] = fmaf(fmaxf(acc[ms][ns][r] + bi, 0.f), wv, pr[ms][r]);
    }
    #pragma unroll
    for (int mask = 1; mask < 16; mask <<= 1)
      #pragma unroll
      for (int ms = 0; ms < 2; ++ms)
        #pragma unroll
        for (int r = 0; r < 4; ++r) pr[ms][r] += __shfl_xor(pr[ms][r], mask);
    if (col == 0) {
      #pragma unroll
      for (int ms = 0; ms < 2; ++ms)
        #pragma unroll
        for (int r = 0; r < 4; ++r) fred[(ms << 4) + (rq << 2) + r][w] = pr[ms][r];
    }
    __syncthreads();
    if (tid < 32) {
      int row = mt0 + tid;
      if (row < M) {
        float s = ((fred[tid][0] + fred[tid][1]) + (fred[tid][2] + fred[tid][3])) + bfp[0];
        outp[sid[row]] = 1.0f / (1.0f + expf(-s));
      }
    }
  } else {
    #pragma unroll
    for (int ms = 0; ms < 2; ++ms) {
      #pragma unroll
      for (int ns = 0; ns < 4; ++ns) {
        int nn = (w << 6) + (ns << 4) + col;
        float bi = bias[nn];
        #pragma unroll
        for (int r = 0; r < 4; ++r) {
          int row = mt0 + (ms << 4) + (rq << 2) + r;
          if (row < M) C[(size_t)row * 256 + nn] = fmaxf(acc[ms][ns][r] + bi, 0.f);
        }
      }
    }
  }
}

extern "C" void kernel_launch(void* const* d_in, const int* in_sizes, int n_in,
                              void* d_out, int out_size, void* d_ws, size_t ws_size,
                              hipStream_t stream) {
  const float* x = (const float*)d_in[0];
  const float* centers = (const float*)d_in[1];
  const float* W0 = (const float*)d_in[2];
  const float* b0 = (const float*)d_in[3];
  const float* W1 = (const float*)d_in[4];
  const float* b1 = (const float*)d_in[5];
  const float* W2 = (const float*)d_in[6];
  const float* b2 = (const float*)d_in[7];
  const float* Wf = (const float*)d_in[8];
  const float* bf = (const float*)d_in[9];
  float* out = (float*)d_out;

  const int N = in_sizes[1] / 3;  // 20000

  char* p = (char*)d_ws;
  auto alloc = [&](size_t bytes) {
    void* r = (void*)p;
    p += (bytes + 255) & ~(size_t)255;
    return r;
  };
  float4* cpack = (float4*)alloc((size_t)N * 16);
  int* deg = (int*)alloc((size_t)N * 4);
  float* srcn = (float*)alloc((size_t)N * 4);
  int* idx = (int*)alloc((size_t)N * KNN * 4);
  float* hA = (float*)alloc((size_t)N * 256 * 4);
  float* P = (float*)alloc(16 * 4);
  int* counts = (int*)alloc((size_t)G3 * 4);
  int* starts = (int*)alloc((size_t)G3 * 4);
  int* cursor = (int*)alloc((size_t)G3 * 4);
  int2* cellinfo = (int2*)alloc((size_t)G3 * 8);
  int* sid = (int*)alloc((size_t)N * 4);
  int* inv = (int*)alloc((size_t)N * 4);
  float4* spack = (float4*)alloc((size_t)N * 16);
  unsigned short* w0h = (unsigned short*)alloc(128 * 256 * 2);
  unsigned short* w0l = (unsigned short*)alloc(128 * 256 * 2);
  unsigned short* w1h = (unsigned short*)alloc(256 * 256 * 2);
  unsigned short* w1l = (unsigned short*)alloc(256 * 256 * 2);
  unsigned short* w2h = (unsigned short*)alloc(256 * 256 * 2);
  unsigned short* w2l = (unsigned short*)alloc(256 * 256 * 2);
  (void)ws_size; (void)n_in; (void)out_size;

  const int nb = (N + 255) / 256;

  prep_kernel<<<256, 256, 0, stream>>>(centers, cpack, deg, counts, cursor, N);
  split_w_kernel<<<(128 / 32) * 1024 / 256, 256, 0, stream>>>(W0, w0h, w0l, 128);
  split_w_kernel<<<(256 / 32) * 1024 / 256, 256, 0, stream>>>(W1, w1h, w1l, 256);
  split_w_kernel<<<(256 / 32) * 1024 / 256, 256, 0, stream>>>(W2, w2h, w2l, 256);
  params_kernel<<<1, 1024, 0, stream>>>(cpack, P, N);
  count_kernel<<<nb, 256, 0, stream>>>(cpack, P, counts, N);
  scan_kernel<<<1, 1024, 0, stream>>>(counts, starts, cellinfo);
  scatter_kernel<<<nb, 256, 0, stream>>>(cpack, P, starts, cursor, sid, inv, spack, N);
  query_kernel<<<N, 64, 0, stream>>>(spack, sid, inv, cellinfo, P, idx, deg, N);
  norm_kernel<<<nb, 256, 0, stream>>>(deg, srcn, N);

  const int ggrid = (((N + 31) / 32) + 7) & ~7;    // 632

  agg_gemm<128><<<ggrid, 256, 0, stream>>>(x, sid, srcn, idx, w0h, w0l, b0, hA, N,
                                           nullptr, nullptr, nullptr, nullptr);
  agg_gemm<256><<<ggrid, 256, 0, stream>>>(hA, nullptr, srcn, idx, w1h, w1l, b1, hA, N,
                                           nullptr, nullptr, nullptr, nullptr);
  agg_gemm<256><<<ggrid, 256, 0, stream>>>(hA, nullptr, srcn, idx, w2h, w2l, b2, nullptr, N,
                                           Wf, bf, sid, out);
}

// Round 14
// 438.644 us; speedup vs baseline: 1.0436x; 1.0436x over previous
//
#include <hip/hip_runtime.h>
#include <math.h>

#define KNN 16
#define G 16
#define G3 4096
#define MRING 15
#define FLTMAX 3.402823466e+38f

typedef __attribute__((ext_vector_type(8))) short short8x;   // 8 x bf16 frag
typedef __attribute__((ext_vector_type(4))) float f32x4;     // MFMA accum

// ---------- bf16 helpers (RNE) ----------
__device__ __forceinline__ unsigned short bf16rn(float x) {
  unsigned u = __float_as_uint(x);
  unsigned r = (u + 0x7FFFu + ((u >> 16) & 1u)) >> 16;
  return (unsigned short)r;
}
__device__ __forceinline__ float bf16tof(unsigned short h) {
  return __uint_as_float(((unsigned)h) << 16);
}

// ---------- order-preserving float<->uint keys ----------
__device__ __forceinline__ unsigned fkey(float f) {
  unsigned u = __float_as_uint(f);
  return (u & 0x80000000u) ? ~u : (u | 0x80000000u);
}
__device__ __forceinline__ float funkey(unsigned u) {
  unsigned b = (u & 0x80000000u) ? (u & 0x7FFFFFFFu) : ~u;
  return __uint_as_float(b);
}

__device__ __forceinline__ void cell_of(float x, float y, float z, const float* P,
                                        int& cx, int& cy, int& cz) {
  cx = min(G - 1, max(0, (int)((x - P[0]) * P[3])));
  cy = min(G - 1, max(0, (int)((y - P[1]) * P[4])));
  cz = min(G - 1, max(0, (int)((z - P[2]) * P[5])));
}

// ---------- stage 1: zero grids + pack centers (init merged) ----------
// sq EXACTLY as R1..R13 (absmax-stable): (x*x + y*y) + z*z, contract off.
__global__ void prep_kernel(const float* __restrict__ centers,
                            float4* __restrict__ cpack, int* __restrict__ deg,
                            int* __restrict__ counts, int* __restrict__ cursor,
                            int n) {
  #pragma clang fp contract(off)
  int t = blockIdx.x * blockDim.x + threadIdx.x;
  if (t < G3) counts[t] = 0;
  else if (t < 2 * G3) cursor[t - G3] = 0;
  if (t < n) {
    float x = centers[3 * t], y = centers[3 * t + 1], z = centers[3 * t + 2];
    float sq = (x * x + y * y) + z * z;
    cpack[t] = make_float4(x, y, z, sq);
    deg[t] = 0;
  }
}

// ---------- stage 2: bbox reduction + grid params, one block -------------
__global__ __launch_bounds__(1024) void params_kernel(const float4* __restrict__ cpack,
                                                      float* __restrict__ P, int n) {
  __shared__ float sminb[16][3], smaxb[16][3];
  int tid = threadIdx.x;
  float mnx = FLTMAX, mny = FLTMAX, mnz = FLTMAX;
  float mxx = -FLTMAX, mxy = -FLTMAX, mxz = -FLTMAX;
  for (int i = tid; i < n; i += 1024) {
    float4 c = cpack[i];
    mnx = fminf(mnx, c.x); mny = fminf(mny, c.y); mnz = fminf(mnz, c.z);
    mxx = fmaxf(mxx, c.x); mxy = fmaxf(mxy, c.y); mxz = fmaxf(mxz, c.z);
  }
  #pragma unroll
  for (int off = 1; off < 64; off <<= 1) {
    mnx = fminf(mnx, __shfl_xor(mnx, off));
    mny = fminf(mny, __shfl_xor(mny, off));
    mnz = fminf(mnz, __shfl_xor(mnz, off));
    mxx = fmaxf(mxx, __shfl_xor(mxx, off));
    mxy = fmaxf(mxy, __shfl_xor(mxy, off));
    mxz = fmaxf(mxz, __shfl_xor(mxz, off));
  }
  if ((tid & 63) == 0) {
    int w = tid >> 6;
    sminb[w][0] = mnx; sminb[w][1] = mny; sminb[w][2] = mnz;
    smaxb[w][0] = mxx; smaxb[w][1] = mxy; smaxb[w][2] = mxz;
  }
  __syncthreads();
  if (tid == 0) {
    float xmin = sminb[0][0], ymin = sminb[0][1], zmin = sminb[0][2];
    float xmax = smaxb[0][0], ymax = smaxb[0][1], zmax = smaxb[0][2];
    for (int w = 1; w < 16; ++w) {
      xmin = fminf(xmin, sminb[w][0]); ymin = fminf(ymin, sminb[w][1]);
      zmin = fminf(zmin, sminb[w][2]);
      xmax = fmaxf(xmax, smaxb[w][0]); ymax = fmaxf(ymax, smaxb[w][1]);
      zmax = fmaxf(zmax, smaxb[w][2]);
    }
    float ex = fmaxf(xmax - xmin, 1e-9f);
    float ey = fmaxf(ymax - ymin, 1e-9f);
    float ez = fmaxf(zmax - zmin, 1e-9f);
    P[0] = xmin; P[1] = ymin; P[2] = zmin;
    P[3] = (float)G / ex; P[4] = (float)G / ey; P[5] = (float)G / ez;
    P[6] = ex / (float)G; P[7] = ey / (float)G; P[8] = ez / (float)G;
    P[9] = fminf(P[6], fminf(P[7], P[8]));
  }
}

// ---------- stage 3 ----------
__global__ void count_kernel(const float4* __restrict__ cpack, const float* __restrict__ P,
                             int* __restrict__ counts, int n) {
  int i = blockIdx.x * blockDim.x + threadIdx.x;
  if (i >= n) return;
  float4 c = cpack[i];
  int cx, cy, cz; cell_of(c.x, c.y, c.z, P, cx, cy, cz);
  atomicAdd(&counts[(cz * G + cy) * G + cx], 1);
}

// ---------- stage 4: exclusive scan of G3=4096 (4/thread) + cellinfo ------
__global__ __launch_bounds__(1024) void scan_kernel(const int* __restrict__ counts,
                                                    int* __restrict__ starts,
                                                    int2* __restrict__ cellinfo) {
  __shared__ int sh[1024];
  int t = threadIdx.x;
  int base = t * 4;
  int loc[4];
  int cnts[4];
  int s = 0;
  #pragma unroll
  for (int u = 0; u < 4; ++u) {
    cnts[u] = counts[base + u];
    loc[u] = s; s += cnts[u];
  }
  sh[t] = s;
  __syncthreads();
  for (int off = 1; off < 1024; off <<= 1) {
    int v = (t >= off) ? sh[t - off] : 0;
    __syncthreads();
    sh[t] += v;
    __syncthreads();
  }
  int pre = (t == 0) ? 0 : sh[t - 1];
  #pragma unroll
  for (int u = 0; u < 4; ++u) {
    int st = pre + loc[u];
    starts[base + u] = st;
    cellinfo[base + u] = make_int2(st, cnts[u]);
  }
}

// ---------- stage 5: scatter + inverse permutation ----------
__global__ void scatter_kernel(const float4* __restrict__ cpack, const float* __restrict__ P,
                               const int* __restrict__ starts, int* __restrict__ cursor,
                               int* __restrict__ sid, int* __restrict__ inv,
                               float4* __restrict__ spack, int n) {
  int i = blockIdx.x * blockDim.x + threadIdx.x;
  if (i >= n) return;
  float4 c = cpack[i];
  int cx, cy, cz; cell_of(c.x, c.y, c.z, P, cx, cy, cz);
  int cell = (cz * G + cy) * G + cx;
  int slot = starts[cell] + atomicAdd(&cursor[cell], 1);
  sid[slot] = i;
  inv[i] = slot;
  spack[slot] = c;
}

// ---------- stage 6: expanding-ring exact kNN (R12 logic, G=16) ----------
// Coarser grid: typical query finishes ring 1 (27 cells, ~130 pts, ONE
// chunk sequence) and terminates at the m=2 bound - vs 3-4 chained chunk
// sequences at G=32. All selection/bound logic is G-generic (exact).
__global__ __launch_bounds__(64) void query_kernel(
    const float4* __restrict__ spack, const int* __restrict__ sid,
    const int* __restrict__ inv, const int2* __restrict__ cellinfo,
    const float* __restrict__ P, int* __restrict__ knn_idx,
    int* __restrict__ deg, int n) {
  #pragma clang fp contract(off)
  __shared__ unsigned long long lsk[KNN][64];  // 8192 B
  const int lane = threadIdx.x;
  const int g = blockIdx.x;
  if (g >= n) return;
  const float4 q = spack[g];
  const float xmin = P[0], ymin = P[1], zmin = P[2];
  const float wx = P[6], wy = P[7], wz = P[8], wmin = P[9];
  int cx, cy, cz; cell_of(q.x, q.y, q.z, P, cx, cy, cz);

  int cnt = 0;
  unsigned long long wkey = 0; int wslot = 0;
  unsigned long long minkey = ~0ull; int minslot = 0;

  for (int m = 1; m <= MRING; ++m) {
    if (m >= 2) {
      float b = (float)(m - 1) * wmin;
      float b2 = b * b * 0.999f;
      unsigned long long tk = ((unsigned long long)fkey(b2)) << 32;
      int c = 0;
      for (int t = 0; t < cnt; ++t) c += (lsk[t][lane] < tk) ? 1 : 0;
      #pragma unroll
      for (int off = 1; off < 64; off <<= 1) c += __shfl_xor(c, off);
      if (c >= KNN) break;
    }
    float lw = (cnt == KNN) ? funkey((unsigned)(wkey >> 32)) : FLTMAX;
    #pragma unroll
    for (int off = 1; off < 64; off <<= 1) lw = fminf(lw, __shfl_xor(lw, off));
    const bool do_prune = (lw < FLTMAX);  // wave-uniform

    const int ncells = (m == 1) ? 27 : (24 * m * m + 2);
    for (int cb = 0; cb < ncells; cb += 64) {
      int f = cb + lane;
      int ccnt = 0, cs0 = 0;
      if (f < ncells) {
        int dx, dy, dz;
        if (m == 1) {
          dz = f / 9 - 1; int rem = f % 9; dy = rem / 3 - 1; dx = rem % 3 - 1;
        } else {
          int side = 2 * m + 1;
          int S1 = side * side;
          if (f < 2 * S1) {
            dz = (f < S1) ? -m : m;
            int i2 = (f < S1) ? f : f - S1;
            dy = i2 / side - m; dx = i2 % side - m;
          } else {
            int r = f - 2 * S1;
            int layer = r / (8 * m);
            int t2 = r - layer * 8 * m;
            dz = layer - (m - 1);
            if (t2 < side) { dy = -m; dx = t2 - m; }
            else if (t2 < 2 * side) { dy = m; dx = (t2 - side) - m; }
            else { int u = t2 - 2 * side; dx = (u & 1) ? m : -m; dy = (u >> 1) - (m - 1); }
          }
        }
        int x = cx + dx, y = cy + dy, z = cz + dz;
        if (x >= 0 && x < G && y >= 0 && y < G && z >= 0 && z < G) {
          int cell = (z * G + y) * G + x;
          int2 ci = cellinfo[cell];
          if (ci.y > 0) {
            bool pass = true;
            if (do_prune) {
              float lox = xmin + (float)x * wx;
              float loy = ymin + (float)y * wy;
              float loz = zmin + (float)z * wz;
              float ddx = fmaxf(fmaxf(lox - q.x, q.x - (lox + wx)), 0.f);
              float ddy = fmaxf(fmaxf(loy - q.y, q.y - (loy + wy)), 0.f);
              float ddz = fmaxf(fmaxf(loz - q.z, q.z - (loz + wz)), 0.f);
              float cd2 = ddx * ddx + ddy * ddy + ddz * ddz;
              pass = !(cd2 * 0.999f > lw);
            }
            if (pass) { ccnt = ci.y; cs0 = ci.x; }
          }
        }
      }
      int inc = ccnt;
      #pragma unroll
      for (int off = 1; off < 64; off <<= 1) {
        int t = __shfl_up(inc, off);
        if (lane >= off) inc += t;
      }
      int total = __shfl(inc, 63);
      if (total == 0) continue;
      unsigned seg = ((unsigned)(inc - ccnt) << 16) | (unsigned)cs0;
      const int tmax = total - 1;

      int fc = lane;
      int fcc = min(fc, tmax);
      int lo = 0;
      #pragma unroll
      for (int s = 32; s >= 1; s >>= 1) {
        int cand = lo + s;
        unsigned o = __shfl(seg, cand & 63);
        if (cand < 64 && (int)(o >> 16) <= fcc) lo = cand;
      }
      unsigned o2 = __shfl(seg, lo);
      int src = (int)(o2 & 0xFFFFu) + (fcc - (int)(o2 >> 16));
      float4 c4 = spack[src];
      int j = sid[src];
      const int nloop = (total + 63) >> 6;
      for (int it = 0; it < nloop; ++it) {
        int fn = fc + 64;
        int fnc = min(fn, tmax);
        int lo2 = 0;
        #pragma unroll
        for (int s = 32; s >= 1; s >>= 1) {
          int cand = lo2 + s;
          unsigned o = __shfl(seg, cand & 63);
          if (cand < 64 && (int)(o >> 16) <= fnc) lo2 = cand;
        }
        unsigned o3 = __shfl(seg, lo2);
        int srcn = (int)(o3 & 0xFFFFu) + (fnc - (int)(o3 >> 16));
        float4 c4n = spack[srcn];
        int jn = sid[srcn];
        if (fc < total) {
          float dot = fmaf(q.z, c4.z, fmaf(q.y, c4.y, q.x * c4.x));
          float d2 = (q.w + c4.w) - 2.0f * dot;
          unsigned long long key =
              (((unsigned long long)fkey(d2)) << 32) | (unsigned)j;
          if (cnt < KNN) {
            lsk[cnt][lane] = key;
            if (key < minkey) { minkey = key; minslot = cnt; }
            ++cnt;
            if (cnt == KNN) {
              wkey = 0; wslot = 0;
              #pragma unroll
              for (int u = 0; u < KNN; ++u) {
                unsigned long long k2 = lsk[u][lane];
                if (k2 > wkey) { wkey = k2; wslot = u; }
              }
            }
          } else if (key < wkey) {
            lsk[wslot][lane] = key;
            if (key < minkey) { minkey = key; minslot = wslot; }
            wkey = 0;
            #pragma unroll
            for (int u = 0; u < KNN; ++u) {
              unsigned long long k2 = lsk[u][lane];
              if (k2 > wkey) { wkey = k2; wslot = u; }
            }
          }
        }
        fc = fn; c4 = c4n; j = jn;
      }
    }
  }

  unsigned long long mykey = 0;
  for (int t = 0; t < KNN; ++t) {
    unsigned long long k = minkey; int src = lane;
    #pragma unroll
    for (int off = 1; off < 64; off <<= 1) {
      unsigned long long ok = __shfl_xor(k, off);
      int os = __shfl_xor(src, off);
      if (ok < k) { k = ok; src = os; }
    }
    if (lane == t) mykey = k;
    if (lane == src) {
      lsk[minslot][lane] = ~0ull;
      minkey = ~0ull; minslot = 0;
      for (int u = 0; u < cnt; ++u) {
        unsigned long long kk = lsk[u][lane];
        if (kk < minkey) { minkey = kk; minslot = u; }
      }
    }
  }
  if (lane < KNN) {
    int j = (int)(unsigned)(mykey & 0xFFFFFFFFull);
    int js = inv[j];
    knn_idx[g * KNN + lane] = js;
    atomicAdd(&deg[js], 1);
  }
}

__global__ void norm_kernel(const int* __restrict__ deg, float* __restrict__ srcn, int n) {
  int i = blockIdx.x * blockDim.x + threadIdx.x;
  if (i < n) {
    float d = (float)max(deg[i], 1);
    srcn[i] = 1.0f / sqrtf(d);
  }
}

// ---------- W split: fp32 W[K][256] -> frag-octet-blocked bf16 hi/lo ------
__global__ void split_w_kernel(const float* __restrict__ W,
                               unsigned short* __restrict__ wbh,
                               unsigned short* __restrict__ wbl, int K) {
  int t = blockIdx.x * blockDim.x + threadIdx.x;
  int noct = (K >> 5) * 1024;
  if (t >= noct) return;
  int kblk = t >> 10;
  int g = (t >> 6) & 15;
  int l = t & 63;
  int n = ((g >> 2) << 6) + ((g & 3) << 4) + (l & 15);
  int kbase = (kblk << 5) + ((l >> 4) << 3);
  #pragma unroll
  for (int j = 0; j < 8; ++j) {
    float w = W[(kbase + j) * 256 + n];
    unsigned short hi = bf16rn(w);
    wbh[t * 8 + j] = hi;
    wbl[t * 8 + j] = bf16rn(w - bf16tof(hi));
  }
}

// XCD-locality swizzle (grid must be multiple of 8).
__device__ __forceinline__ int xcd_swizzle(int b, int grid8) {
  int nch = grid8 >> 3;
  return (b & 7) * nch + (b >> 3);
}

// agg (sorted space), fp32 k-loop in rank order (bitwise-same sums)
template <int F>
__global__ __launch_bounds__(256) void agg_kernel(const float* __restrict__ h,
                                                  const int* __restrict__ rmap,
                                                  const float* __restrict__ srcn,
                                                  const int* __restrict__ idx,
                                                  unsigned short* __restrict__ ah,
                                                  unsigned short* __restrict__ al,
                                                  int n) {
  const int lane = threadIdx.x & 63;
  const int wv = threadIdx.x >> 6;
  const int eb = xcd_swizzle(blockIdx.x, gridDim.x);
  const int i = eb * 4 + wv;
  if (i >= n) return;
  constexpr int V = F / 64;
  if constexpr (V == 4) {
    float4 acc = make_float4(0.f, 0.f, 0.f, 0.f);
    #pragma unroll
    for (int k = 0; k < KNN; ++k) {
      int s = idx[i * KNN + k];
      float sn = srcn[s];
      int row = rmap ? rmap[s] : s;
      float4 hv = ((const float4*)(h + (size_t)row * F))[lane];
      acc.x = fmaf(sn, hv.x, acc.x);
      acc.y = fmaf(sn, hv.y, acc.y);
      acc.z = fmaf(sn, hv.z, acc.z);
      acc.w = fmaf(sn, hv.w, acc.w);
    }
    acc.x *= 0.25f; acc.y *= 0.25f; acc.z *= 0.25f; acc.w *= 0.25f;
    ushort4 hh, ll;
    hh.x = bf16rn(acc.x); ll.x = bf16rn(acc.x - bf16tof(hh.x));
    hh.y = bf16rn(acc.y); ll.y = bf16rn(acc.y - bf16tof(hh.y));
    hh.z = bf16rn(acc.z); ll.z = bf16rn(acc.z - bf16tof(hh.z));
    hh.w = bf16rn(acc.w); ll.w = bf16rn(acc.w - bf16tof(hh.w));
    ((ushort4*)(ah + (size_t)i * F))[lane] = hh;
    ((ushort4*)(al + (size_t)i * F))[lane] = ll;
  } else {
    float2 acc = make_float2(0.f, 0.f);
    #pragma unroll
    for (int k = 0; k < KNN; ++k) {
      int s = idx[i * KNN + k];
      float sn = srcn[s];
      int row = rmap ? rmap[s] : s;
      float2 hv = ((const float2*)(h + (size_t)row * F))[lane];
      acc.x = fmaf(sn, hv.x, acc.x);
      acc.y = fmaf(sn, hv.y, acc.y);
    }
    acc.x *= 0.25f; acc.y *= 0.25f;
    ushort2 hh, ll;
    hh.x = bf16rn(acc.x); ll.x = bf16rn(acc.x - bf16tof(hh.x));
    hh.y = bf16rn(acc.y); ll.y = bf16rn(acc.y - bf16tof(hh.y));
    ((ushort2*)(ah + (size_t)i * F))[lane] = hh;
    ((ushort2*)(al + (size_t)i * F))[lane] = ll;
  }
}

// ---------- split-bf16 MFMA GEMM; optional fused final (Wf != nullptr) ----
__global__ __launch_bounds__(256) void gemm_mfma(
    const unsigned short* __restrict__ ah, const unsigned short* __restrict__ al,
    const unsigned short* __restrict__ wbh, const unsigned short* __restrict__ wbl,
    const float* __restrict__ bias, float* __restrict__ C, int M, int Kd,
    const float* __restrict__ Wf, const float* __restrict__ bfp,
    const int* __restrict__ sid, float* __restrict__ outp) {
  __shared__ unsigned short sa_h[2][64][8];
  __shared__ unsigned short sa_l[2][64][8];
  __shared__ unsigned short sb_h[16][64][8];
  __shared__ unsigned short sb_l[16][64][8];
  __shared__ float fred[32][4];
  const int tid = threadIdx.x;
  const int lane = tid & 63;
  const int w = tid >> 6;
  const int eb = xcd_swizzle(blockIdx.x, gridDim.x);
  const int mt0 = eb * 32;
  if (mt0 >= M) return;

  f32x4 acc[2][4];
  #pragma unroll
  for (int ms = 0; ms < 2; ++ms)
    #pragma unroll
    for (int ns = 0; ns < 4; ++ns) acc[ms][ns] = (f32x4){0.f, 0.f, 0.f, 0.f};

  const int nkb = Kd >> 5;
  for (int kit = 0; kit < nkb; ++kit) {
    const int k0 = kit << 5;
    if (tid < 128) {
      int msub = tid >> 6, l = tid & 63;
      int row = mt0 + (msub << 4) + (l & 15);
      int kk = k0 + ((l >> 4) << 3);
      if (row < M) {
        *(uint4*)&sa_h[msub][l][0] = *(const uint4*)(ah + (size_t)row * Kd + kk);
        *(uint4*)&sa_l[msub][l][0] = *(const uint4*)(al + (size_t)row * Kd + kk);
      } else {
        uint4 z = make_uint4(0, 0, 0, 0);
        *(uint4*)&sa_h[msub][l][0] = z;
        *(uint4*)&sa_l[msub][l][0] = z;
      }
    }
    #pragma unroll
    for (int o = tid; o < 1024; o += 256) {
      size_t off = ((size_t)kit * 1024 + o) * 8;
      *(uint4*)&sb_h[o >> 6][o & 63][0] = *(const uint4*)(wbh + off);
      *(uint4*)&sb_l[o >> 6][o & 63][0] = *(const uint4*)(wbl + off);
    }
    __syncthreads();
    short8x a_h0 = *(const short8x*)&sa_h[0][lane][0];
    short8x a_h1 = *(const short8x*)&sa_h[1][lane][0];
    short8x a_l0 = *(const short8x*)&sa_l[0][lane][0];
    short8x a_l1 = *(const short8x*)&sa_l[1][lane][0];
    #pragma unroll
    for (int ns = 0; ns < 4; ++ns) {
      short8x b_h = *(const short8x*)&sb_h[w * 4 + ns][lane][0];
      short8x b_l = *(const short8x*)&sb_l[w * 4 + ns][lane][0];
      acc[0][ns] = __builtin_amdgcn_mfma_f32_16x16x32_bf16(a_h0, b_h, acc[0][ns], 0, 0, 0);
      acc[0][ns] = __builtin_amdgcn_mfma_f32_16x16x32_bf16(a_h0, b_l, acc[0][ns], 0, 0, 0);
      acc[0][ns] = __builtin_amdgcn_mfma_f32_16x16x32_bf16(a_l0, b_h, acc[0][ns], 0, 0, 0);
      acc[1][ns] = __builtin_amdgcn_mfma_f32_16x16x32_bf16(a_h1, b_h, acc[1][ns], 0, 0, 0);
      acc[1][ns] = __builtin_amdgcn_mfma_f32_16x16x32_bf16(a_h1, b_l, acc[1][ns], 0, 0, 0);
      acc[1][ns] = __builtin_amdgcn_mfma_f32_16x16x32_bf16(a_l1, b_h, acc[1][ns], 0, 0, 0);
    }
    __syncthreads();
  }

  const int col = lane & 15;
  const int rq = lane >> 4;
  if (Wf) {
    float pr[2][4];
    #pragma unroll
    for (int ms = 0; ms < 2; ++ms)
      #pragma unroll
      for (int r = 0; r < 4; ++r) pr[ms][r] = 0.f;
    #pragma unroll
    for (int ns = 0; ns < 4; ++ns) {
      int nn = (w << 6) + (ns << 4) + col;
      float bi = bias[nn];
      float wv = Wf[nn];
      #pragma unroll
      for (int ms = 0; ms < 2; ++ms)
        #pragma unroll
        for (int r = 0; r < 4; ++r)
          pr[ms][r] = fmaf(fmaxf(acc[ms][ns][r] + bi, 0.f), wv, pr[ms][r]);
    }
    #pragma unroll
    for (int mask = 1; mask < 16; mask <<= 1)
      #pragma unroll
      for (int ms = 0; ms < 2; ++ms)
        #pragma unroll
        for (int r = 0; r < 4; ++r) pr[ms][r] += __shfl_xor(pr[ms][r], mask);
    if (col == 0) {
      #pragma unroll
      for (int ms = 0; ms < 2; ++ms)
        #pragma unroll
        for (int r = 0; r < 4; ++r) fred[(ms << 4) + (rq << 2) + r][w] = pr[ms][r];
    }
    __syncthreads();
    if (tid < 32) {
      int row = mt0 + tid;
      if (row < M) {
        float s = ((fred[tid][0] + fred[tid][1]) + (fred[tid][2] + fred[tid][3])) + bfp[0];
        outp[sid[row]] = 1.0f / (1.0f + expf(-s));
      }
    }
  } else {
    #pragma unroll
    for (int ms = 0; ms < 2; ++ms) {
      #pragma unroll
      for (int ns = 0; ns < 4; ++ns) {
        int nn = (w << 6) + (ns << 4) + col;
        float bi = bias[nn];
        #pragma unroll
        for (int r = 0; r < 4; ++r) {
          int row = mt0 + (ms << 4) + (rq << 2) + r;
          if (row < M) C[(size_t)row * 256 + nn] = fmaxf(acc[ms][ns][r] + bi, 0.f);
        }
      }
    }
  }
}

extern "C" void kernel_launch(void* const* d_in, const int* in_sizes, int n_in,
                              void* d_out, int out_size, void* d_ws, size_t ws_size,
                              hipStream_t stream) {
  const float* x = (const float*)d_in[0];
  const float* centers = (const float*)d_in[1];
  const float* W0 = (const float*)d_in[2];
  const float* b0 = (const float*)d_in[3];
  const float* W1 = (const float*)d_in[4];
  const float* b1 = (const float*)d_in[5];
  const float* W2 = (const float*)d_in[6];
  const float* b2 = (const float*)d_in[7];
  const float* Wf = (const float*)d_in[8];
  const float* bf = (const float*)d_in[9];
  float* out = (float*)d_out;

  const int N = in_sizes[1] / 3;  // 20000

  char* p = (char*)d_ws;
  auto alloc = [&](size_t bytes) {
    void* r = (void*)p;
    p += (bytes + 255) & ~(size_t)255;
    return r;
  };
  float4* cpack = (float4*)alloc((size_t)N * 16);
  int* deg = (int*)alloc((size_t)N * 4);
  float* srcn = (float*)alloc((size_t)N * 4);
  int* idx = (int*)alloc((size_t)N * KNN * 4);
  unsigned short* ahb = (unsigned short*)alloc((size_t)N * 256 * 2);
  unsigned short* alb = (unsigned short*)alloc((size_t)N * 256 * 2);
  float* hA = (float*)alloc((size_t)N * 256 * 4);
  float* P = (float*)alloc(16 * 4);
  int* counts = (int*)alloc((size_t)G3 * 4);
  int* starts = (int*)alloc((size_t)G3 * 4);
  int* cursor = (int*)alloc((size_t)G3 * 4);
  int2* cellinfo = (int2*)alloc((size_t)G3 * 8);
  int* sid = (int*)alloc((size_t)N * 4);
  int* inv = (int*)alloc((size_t)N * 4);
  float4* spack = (float4*)alloc((size_t)N * 16);
  unsigned short* w0h = (unsigned short*)alloc(128 * 256 * 2);
  unsigned short* w0l = (unsigned short*)alloc(128 * 256 * 2);
  unsigned short* w1h = (unsigned short*)alloc(256 * 256 * 2);
  unsigned short* w1l = (unsigned short*)alloc(256 * 256 * 2);
  unsigned short* w2h = (unsigned short*)alloc(256 * 256 * 2);
  unsigned short* w2l = (unsigned short*)alloc(256 * 256 * 2);
  (void)ws_size; (void)n_in; (void)out_size;

  const int nb = (N + 255) / 256;

  prep_kernel<<<256, 256, 0, stream>>>(centers, cpack, deg, counts, cursor, N);
  split_w_kernel<<<(128 / 32) * 1024 / 256, 256, 0, stream>>>(W0, w0h, w0l, 128);
  split_w_kernel<<<(256 / 32) * 1024 / 256, 256, 0, stream>>>(W1, w1h, w1l, 256);
  split_w_kernel<<<(256 / 32) * 1024 / 256, 256, 0, stream>>>(W2, w2h, w2l, 256);
  params_kernel<<<1, 1024, 0, stream>>>(cpack, P, N);
  count_kernel<<<nb, 256, 0, stream>>>(cpack, P, counts, N);
  scan_kernel<<<1, 1024, 0, stream>>>(counts, starts, cellinfo);
  scatter_kernel<<<nb, 256, 0, stream>>>(cpack, P, starts, cursor, sid, inv, spack, N);
  query_kernel<<<N, 64, 0, stream>>>(spack, sid, inv, cellinfo, P, idx, deg, N);
  norm_kernel<<<nb, 256, 0, stream>>>(deg, srcn, N);

  const int agrid = ((N + 3) / 4 + 7) & ~7;        // 5000
  const int ggrid = (((N + 31) / 32) + 7) & ~7;    // 632

  agg_kernel<128><<<agrid, 256, 0, stream>>>(x, sid, srcn, idx, ahb, alb, N);
  gemm_mfma<<<ggrid, 256, 0, stream>>>(ahb, alb, w0h, w0l, b0, hA, N, 128,
                                       nullptr, nullptr, nullptr, nullptr);

  agg_kernel<256><<<agrid, 256, 0, stream>>>(hA, nullptr, srcn, idx, ahb, alb, N);
  gemm_mfma<<<ggrid, 256, 0, stream>>>(ahb, alb, w1h, w1l, b1, hA, N, 256,
                                       nullptr, nullptr, nullptr, nullptr);

  agg_kernel<256><<<agrid, 256, 0, stream>>>(hA, nullptr, srcn, idx, ahb, alb, N);
  gemm_mfma<<<ggrid, 256, 0, stream>>>(ahb, alb, w2h, w2l, b2, nullptr, N, 256,
                                       Wf, bf, sid, out);
}